// Round 6
// baseline (183.199 us; speedup 1.0000x reference)
//
#include <hip/hip_runtime.h>

// RGCN basis-decomposition layer, MI355X (gfx950).
//
// Algebra (torch-.view quirk folded out):
//   U[n][k*4+b] = sum_{j<8} h[n][k*8+j] * w_comp[j][b]     (fold, [N,128], bf16)
//   out = relu(sum_r (sum_{e:dst=d,et=r} U[src_e]) @ Bv[r] + bias)
//
// R6: aggregate and GEMM fused into one kernel. Per 32-node block: 8 waves
// gather edge U-rows into fp32 register accumulators (4 nodes x 8 rels x
// float2/lane), dump to a 70KB bf16 LDS tile, then MFMA straight from LDS
// with the R5-packed B fragments. Kills the 41MB S write + 22MB re-fetch +
// one dispatch. Bp[ct][r][ks][lane][8] packing unchanged (verified R5).

#define N_NODES  20000
#define N_EDGES  320000
#define IN_DIM   256
#define OUT_DIM  256
#define NUM_RELS 8
#define KDIM     128
#define M_PAD    20032          // 626 * 32
#define CAP      96             // bucket capacity per dst node (avg deg 16)

#define FOLD_BLOCKS 2500        // N_NODES*32 / 256
#define FILL_BLOCKS 1250        // N_EDGES / 256
#define BP_BLOCKS   128         // 8ct*8r*8ks*64lane fragments / 256 thr

#define SROW 1096               // LDS row stride (shorts): 8*136+8, ≡4 mod 32 dwords

typedef __attribute__((ext_vector_type(8)))  short short8;
typedef __attribute__((ext_vector_type(16))) float float16v;

static __device__ __forceinline__ unsigned f2bf_rne(float x) {
    unsigned u = __float_as_uint(x);
    return (u + 0x7fffu + ((u >> 16) & 1u)) >> 16;
}
static __device__ __forceinline__ float bf2f(unsigned b) {
    return __uint_as_float(b << 16);
}

// ----------------------------------------------------------------- prep ----
// blockIdx [0, FOLD)           : fold h -> U (bf16)
// blockIdx [FOLD, FOLD+FILL)   : bucket-fill edges by dst
// blockIdx [FOLD+FILL, ...+BP) : basis -> Bp (bf16, MFMA-fragment order)
__global__ __launch_bounds__(256)
void prep_kernel(const float* __restrict__ h, const float* __restrict__ w_comp,
                 unsigned short* __restrict__ U,
                 const int* __restrict__ src, const int* __restrict__ dst,
                 const int* __restrict__ et,
                 int* __restrict__ cnt, int* __restrict__ bucket,
                 const float* __restrict__ basis, unsigned short* __restrict__ Bp) {
    int b = blockIdx.x;
    int t = threadIdx.x;
    if (b < FOLD_BLOCKS) {
        // thread computes U[n][k*4 .. k*4+3]
        int gid = b * 256 + t;                 // over N_NODES*32
        int n = gid >> 5, k = gid & 31;
        const float* hp = h + (size_t)n * IN_DIM + k * 8;
        float4 h0 = *(const float4*)hp;
        float4 h1 = *(const float4*)(hp + 4);
        float hv[8] = {h0.x, h0.y, h0.z, h0.w, h1.x, h1.y, h1.z, h1.w};
        float a0 = 0.f, a1 = 0.f, a2 = 0.f, a3 = 0.f;
#pragma unroll
        for (int j = 0; j < 8; ++j) {
            float hj = hv[j];
            a0 += hj * w_comp[j * 4 + 0];
            a1 += hj * w_comp[j * 4 + 1];
            a2 += hj * w_comp[j * 4 + 2];
            a3 += hj * w_comp[j * 4 + 3];
        }
        uint2 p;
        p.x = f2bf_rne(a0) | (f2bf_rne(a1) << 16);
        p.y = f2bf_rne(a2) | (f2bf_rne(a3) << 16);
        *(uint2*)(U + ((size_t)n << 7) + k * 4) = p;
    } else if (b < FOLD_BLOCKS + FILL_BLOCKS) {
        int e = (b - FOLD_BLOCKS) * 256 + t;
        int d = dst[e];
        int p = atomicAdd(&cnt[d], 1);
        if (p < CAP) bucket[(size_t)d * CAP + p] = src[e] | (et[e] << 16);
    } else {
        // one B fragment (16B) per thread, MFMA fragment order:
        // Bp[((ct*8+r)*8+ks)*64+lane][j] =
        //   bf16(basis[(r*128+ks*16+(lane>>5)*8+j)*256 + ct*32+(lane&31)])
        int frag = (b - FOLD_BLOCKS - FILL_BLOCKS) * 256 + t;   // [0, 32768)
        int lane = frag & 63;
        int ks   = (frag >> 6) & 7;
        int r    = (frag >> 9) & 7;
        int ct   = frag >> 12;
        int o  = ct * 32 + (lane & 31);
        int kb = r * 128 + ks * 16 + (lane >> 5) * 8;
        const float* bsp = basis + (size_t)kb * 256 + o;
        unsigned v[8];
#pragma unroll
        for (int j = 0; j < 8; ++j) v[j] = f2bf_rne(bsp[(size_t)j * 256]);
        uint4 p;
        p.x = v[0] | (v[1] << 16);
        p.y = v[2] | (v[3] << 16);
        p.z = v[4] | (v[5] << 16);
        p.w = v[6] | (v[7] << 16);
        *(uint4*)(Bp + (size_t)frag * 8) = p;
    }
}

// ---------------------------------------------------- fused agg + gemm ----
// Block: 32 dst nodes, 512 thr = 8 waves, grid 626.
// Phase 1 (gather): wave w owns nodes w*4..w*4+3; per edge, 64 lanes read the
//   256B U row; accumulate fp32 in acc[node][rel] (float2/lane = 64 VGPRs).
// Phase 2: dump acc -> bf16 LDS Sacc[32][SROW] ([node][r*136+k]).
// Phase 3 (MFMA): wave w -> cols w*32; A-frags from LDS, B-frags from packed
//   Bp (L2-hot); epilogue bias+relu, C/D layout as verified.
__global__ __launch_bounds__(512)
void agemm_kernel(const unsigned short* __restrict__ U,
                  const int* __restrict__ cnt,
                  const int* __restrict__ bucket,
                  const unsigned short* __restrict__ Bp,
                  const float* __restrict__ bias,
                  float* __restrict__ out) {
    __shared__ unsigned short Sacc[32][SROW];
    int t = threadIdx.x;
    int w = t >> 6, lane = t & 63;
    int ln = lane & 31, hi = lane >> 5;
    int n0 = blockIdx.x * 32;

    float2 acc[4][NUM_RELS];
#pragma unroll
    for (int i = 0; i < 4; ++i)
#pragma unroll
        for (int r = 0; r < NUM_RELS; ++r) { acc[i][r].x = 0.f; acc[i][r].y = 0.f; }

    // ---- phase 1: gather ----
#pragma unroll
    for (int i = 0; i < 4; ++i) {
        int d = n0 + w * 4 + i;
        if (d < N_NODES) {
            int n = cnt[d];
            if (n > CAP) n = CAP;
            const int4* bp4 = (const int4*)(bucket + (size_t)d * CAP);
            int4 e4 = bp4[0];
            for (int ii = 0; ii < n; ii += 4) {
                int4 cur = e4;
                e4 = bp4[(ii >> 2) + 1];       // prefetch (bucket has slack)
                int m = n - ii;
                int es[4] = {cur.x, cur.y, cur.z, cur.w};
#pragma unroll
                for (int j = 0; j < 4; ++j) {
                    if (j < m) {
                        int e = es[j];
                        int s = e & 0xffff;
                        int r = __builtin_amdgcn_readfirstlane(e >> 16);
                        unsigned u = *(const unsigned*)(U + ((size_t)s << 7) + lane * 2);
                        float fx = bf2f(u & 0xffffu), fy = bf2f(u >> 16);
                        switch (r) {
                            case 0: acc[i][0].x += fx; acc[i][0].y += fy; break;
                            case 1: acc[i][1].x += fx; acc[i][1].y += fy; break;
                            case 2: acc[i][2].x += fx; acc[i][2].y += fy; break;
                            case 3: acc[i][3].x += fx; acc[i][3].y += fy; break;
                            case 4: acc[i][4].x += fx; acc[i][4].y += fy; break;
                            case 5: acc[i][5].x += fx; acc[i][5].y += fy; break;
                            case 6: acc[i][6].x += fx; acc[i][6].y += fy; break;
                            default: acc[i][7].x += fx; acc[i][7].y += fy; break;
                        }
                    }
                }
            }
        }
    }

    // ---- phase 2: dump to LDS (bf16) ----
#pragma unroll
    for (int i = 0; i < 4; ++i) {
        int dl = w * 4 + i;
#pragma unroll
        for (int r = 0; r < NUM_RELS; ++r) {
            unsigned p = f2bf_rne(acc[i][r].x) | (f2bf_rne(acc[i][r].y) << 16);
            *(unsigned*)&Sacc[dl][r * 136 + lane * 2] = p;
        }
    }
    __syncthreads();

    // ---- phase 3: MFMA ----
    int c0 = w * 32;
    float16v facc = {};
#pragma unroll
    for (int r = 0; r < NUM_RELS; ++r) {
        const unsigned short* bpr = Bp + (((size_t)(w * 8 + r) * 8) << 9) + lane * 8;
#pragma unroll
        for (int ks = 0; ks < 8; ++ks) {
            short8 a  = *(const short8*)&Sacc[ln][r * 136 + ks * 16 + hi * 8];
            short8 bo = *(const short8*)(bpr + (ks << 9));
            facc = __builtin_amdgcn_mfma_f32_32x32x16_bf16(a, bo, facc, 0, 0, 0);
        }
    }

    // epilogue: C/D layout col=lane&31, row=(reg&3)+8*(reg>>2)+4*(lane>>5)
    float bs = bias[c0 + ln];
#pragma unroll
    for (int reg = 0; reg < 16; ++reg) {
        int row = (reg & 3) + 8 * (reg >> 2) + 4 * hi;
        int n = n0 + row;
        if (n < N_NODES)
            out[(size_t)n * OUT_DIM + c0 + ln] = fmaxf(facc[reg] + bs, 0.f);
    }
}

// --------------------------------------------------------------- launch ----
extern "C" void kernel_launch(void* const* d_in, const int* in_sizes, int n_in,
                              void* d_out, int out_size, void* d_ws, size_t ws_size,
                              hipStream_t stream) {
    const float* h      = (const float*)d_in[0];
    const float* basis  = (const float*)d_in[1];
    const float* w_comp = (const float*)d_in[2];
    const float* bias   = (const float*)d_in[3];
    const int*   src    = (const int*)d_in[4];
    const int*   dst    = (const int*)d_in[5];
    const int*   etype  = (const int*)d_in[6];
    float*       out    = (float*)d_out;

    char* ws = (char*)d_ws;
    size_t off = 0;
    unsigned short* U   = (unsigned short*)(ws + off); off += (size_t)N_NODES * KDIM * 2;     // 5.12 MB
    unsigned short* Bp  = (unsigned short*)(ws + off); off += (size_t)8 * 8 * 8 * 64 * 8 * 2; // 0.52 MB
    int* cnt    = (int*)(ws + off); off += (size_t)M_PAD * 4;                                 // 80 KB
    int* bucket = (int*)(ws + off); off += ((size_t)M_PAD * CAP + 16) * 4;                    // 7.7 MB (+slack)

    hipMemsetAsync(cnt, 0, (size_t)N_NODES * 4, stream);

    prep_kernel<<<FOLD_BLOCKS + FILL_BLOCKS + BP_BLOCKS, 256, 0, stream>>>(
        h, w_comp, U, src, dst, etype, cnt, bucket, basis, Bp);

    agemm_kernel<<<M_PAD / 32, 512, 0, stream>>>(U, cnt, bucket, Bp, bias, out);
}

// Round 7
// 148.710 us; speedup vs baseline: 1.2319x; 1.2319x over previous
//
#include <hip/hip_runtime.h>

// RGCN basis-decomposition layer, MI355X (gfx950).
//
// Algebra (torch-.view quirk folded out):
//   U[n][k*4+b] = sum_{j<8} h[n][k*8+j] * w_comp[j][b]     (fold, [N,128], bf16)
//   S[r][d]     = sum_{e: dst=d, et=r} U[src_e]            (bucketed aggregate)
//   out         = relu(sum_r S[r] @ Bv[r] + bias)          (bf16 MFMA GEMM, K=8*128)
//
// R7: fusion reverted (R6: 70KB LDS -> 26% occ + barrier-coupled gather =
// 87us vs 56us split). Aggregate gather MLP deepened 4 -> 8 (all 8 U-row
// gathers issued before any consume; accumulate predicated by uniform m).

#define N_NODES  20000
#define N_EDGES  320000
#define IN_DIM   256
#define OUT_DIM  256
#define NUM_RELS 8
#define KDIM     128
#define M_PAD    20032          // 626 * 32
#define CAP      96             // bucket capacity per dst node (avg deg 16)

#define FOLD_BLOCKS 2500        // N_NODES*32 / 256
#define FILL_BLOCKS 1250        // N_EDGES / 256
#define BP_BLOCKS   128         // 8ct*8r*8ks*64lane fragments / 256 thr

typedef __attribute__((ext_vector_type(8)))  short short8;
typedef __attribute__((ext_vector_type(16))) float float16v;

static __device__ __forceinline__ unsigned f2bf_rne(float x) {
    unsigned u = __float_as_uint(x);
    return (u + 0x7fffu + ((u >> 16) & 1u)) >> 16;
}
static __device__ __forceinline__ float bf2f(unsigned b) {
    return __uint_as_float(b << 16);
}

// ----------------------------------------------------------------- prep ----
// blockIdx [0, FOLD)           : fold h -> U (bf16)
// blockIdx [FOLD, FOLD+FILL)   : bucket-fill edges by dst
// blockIdx [FOLD+FILL, ...+BP) : basis -> Bp (bf16, MFMA-fragment order)
__global__ __launch_bounds__(256)
void prep_kernel(const float* __restrict__ h, const float* __restrict__ w_comp,
                 unsigned short* __restrict__ U,
                 const int* __restrict__ src, const int* __restrict__ dst,
                 const int* __restrict__ et,
                 int* __restrict__ cnt, int* __restrict__ bucket,
                 const float* __restrict__ basis, unsigned short* __restrict__ Bp) {
    int b = blockIdx.x;
    int t = threadIdx.x;
    if (b < FOLD_BLOCKS) {
        // thread computes U[n][k*4 .. k*4+3]
        int gid = b * 256 + t;                 // over N_NODES*32
        int n = gid >> 5, k = gid & 31;
        const float* hp = h + (size_t)n * IN_DIM + k * 8;
        float4 h0 = *(const float4*)hp;
        float4 h1 = *(const float4*)(hp + 4);
        float hv[8] = {h0.x, h0.y, h0.z, h0.w, h1.x, h1.y, h1.z, h1.w};
        float a0 = 0.f, a1 = 0.f, a2 = 0.f, a3 = 0.f;
#pragma unroll
        for (int j = 0; j < 8; ++j) {
            float hj = hv[j];
            a0 += hj * w_comp[j * 4 + 0];
            a1 += hj * w_comp[j * 4 + 1];
            a2 += hj * w_comp[j * 4 + 2];
            a3 += hj * w_comp[j * 4 + 3];
        }
        uint2 p;
        p.x = f2bf_rne(a0) | (f2bf_rne(a1) << 16);
        p.y = f2bf_rne(a2) | (f2bf_rne(a3) << 16);
        *(uint2*)(U + ((size_t)n << 7) + k * 4) = p;
    } else if (b < FOLD_BLOCKS + FILL_BLOCKS) {
        int e = (b - FOLD_BLOCKS) * 256 + t;
        int d = dst[e];
        int p = atomicAdd(&cnt[d], 1);
        if (p < CAP) bucket[(size_t)d * CAP + p] = src[e] | (et[e] << 16);
    } else {
        // one B fragment (16B) per thread, MFMA fragment order:
        // Bp[((ct*8+r)*8+ks)*64+lane][j] =
        //   bf16(basis[(r*128+ks*16+(lane>>5)*8+j)*256 + ct*32+(lane&31)])
        int frag = (b - FOLD_BLOCKS - FILL_BLOCKS) * 256 + t;   // [0, 32768)
        int lane = frag & 63;
        int ks   = (frag >> 6) & 7;
        int r    = (frag >> 9) & 7;
        int ct   = frag >> 12;
        int o  = ct * 32 + (lane & 31);
        int kb = r * 128 + ks * 16 + (lane >> 5) * 8;
        const float* bsp = basis + (size_t)kb * 256 + o;
        unsigned v[8];
#pragma unroll
        for (int j = 0; j < 8; ++j) v[j] = f2bf_rne(bsp[(size_t)j * 256]);
        uint4 p;
        p.x = v[0] | (v[1] << 16);
        p.y = v[2] | (v[3] << 16);
        p.z = v[4] | (v[5] << 16);
        p.w = v[6] | (v[7] << 16);
        *(uint4*)(Bp + (size_t)frag * 8) = p;
    }
}

// ------------------------------------------------------------ aggregate ----
// One wave per dst node. 8-deep gather pipeline: two int4 bucket batches are
// kept in flight and all 8 U-row gathers issue before any accumulate.
// OOB gathers (j >= m) read in-workspace garbage and are discarded; the
// accumulate predicate m is wave-uniform (scalar branch).
__global__ __launch_bounds__(256)
void aggregate_kernel(const unsigned short* __restrict__ U,
                      const int* __restrict__ cnt,
                      const int* __restrict__ bucket,
                      unsigned int* __restrict__ S) {  // S as uint (2 bf16)
    int wid  = threadIdx.x >> 6;
    int lane = threadIdx.x & 63;
    int d = blockIdx.x * 4 + wid;          // < 20032
    float2 acc[NUM_RELS];
#pragma unroll
    for (int r = 0; r < NUM_RELS; ++r) { acc[r].x = 0.f; acc[r].y = 0.f; }

    if (d < N_NODES) {
        int n = cnt[d];
        if (n > CAP) n = CAP;
        const int4* bp4 = (const int4*)(bucket + (size_t)d * CAP);
        int4 ea = bp4[0], eb = bp4[1];
        for (int i = 0; i < n; i += 8) {
            int4 c0 = ea, c1 = eb;
            ea = bp4[(i >> 2) + 2];        // prefetch next batch (slack ok)
            eb = bp4[(i >> 2) + 3];
            int m = n - i;
            int es[8] = {c0.x, c0.y, c0.z, c0.w, c1.x, c1.y, c1.z, c1.w};
            unsigned uv[8];
#pragma unroll
            for (int j = 0; j < 8; ++j) {   // issue all 8 gathers up front
                int s = es[j] & 0xffff;
                uv[j] = *(const unsigned*)(U + ((size_t)s << 7) + lane * 2);
            }
#pragma unroll
            for (int j = 0; j < 8; ++j) {
                if (j < m) {                 // m wave-uniform -> scalar branch
                    int r = __builtin_amdgcn_readfirstlane(es[j] >> 16);
                    float fx = bf2f(uv[j] & 0xffffu), fy = bf2f(uv[j] >> 16);
                    switch (r) {
                        case 0: acc[0].x += fx; acc[0].y += fy; break;
                        case 1: acc[1].x += fx; acc[1].y += fy; break;
                        case 2: acc[2].x += fx; acc[2].y += fy; break;
                        case 3: acc[3].x += fx; acc[3].y += fy; break;
                        case 4: acc[4].x += fx; acc[4].y += fy; break;
                        case 5: acc[5].x += fx; acc[5].y += fy; break;
                        case 6: acc[6].x += fx; acc[6].y += fy; break;
                        default: acc[7].x += fx; acc[7].y += fy; break;
                    }
                }
            }
        }
    }
#pragma unroll
    for (int r = 0; r < NUM_RELS; ++r) {
        unsigned p = f2bf_rne(acc[r].x) | (f2bf_rne(acc[r].y) << 16);
        S[(((size_t)r * M_PAD + d) << 6) + lane] = p;
    }
}

// ----------------------------------------------------------------- gemm ----
// out[n][o] = relu(sum_{r,k} S[r][n][k] * Bp-frag + bias[o])
// 512 thr = 8 waves; C tile 32 rows x 256 cols; wave w -> one 32x32 MFMA
// tile at cols w*32. Grid 626. A staged once via LDS (VGPR prefetch of the
// next relation); B fragments read coalesced from packed Bp (L2-resident).
__global__ __launch_bounds__(512)
void gemm_kernel(const unsigned short* __restrict__ S,
                 const unsigned short* __restrict__ Bp,
                 const float* __restrict__ bias,
                 float* __restrict__ out) {
    __shared__ unsigned short At[32][136];
    int t = threadIdx.x;
    int w = t >> 6, lane = t & 63;
    int ln = lane & 31, hi = lane >> 5;
    int n0 = blockIdx.x * 32;
    int c0 = w * 32;

    int srow = t >> 4, sq = t & 15;        // staging: 512 x 16B = 32 rows x 256B
    const unsigned short* sbase = S + (((size_t)n0 + srow) << 7) + sq * 8;
    uint4 pre = *(const uint4*)sbase;      // r=0 A-tile fragment

    float16v acc = {};

    for (int r = 0; r < NUM_RELS; ++r) {
        if (r > 0) __syncthreads();        // prev iter's LDS reads complete
        *(uint4*)&At[srow][sq * 8] = pre;
        __syncthreads();
        if (r + 1 < NUM_RELS)
            pre = *(const uint4*)(sbase + (((size_t)(r + 1) * M_PAD) << 7));
        // packed B: fragment base for (ct=w, r, ks), 1KB contiguous per wave
        const unsigned short* bpr = Bp + (((size_t)(w * 8 + r) * 8) << 9) + lane * 8;
#pragma unroll
        for (int ks = 0; ks < 8; ++ks) {
            short8 a  = *(const short8*)&At[ln][ks * 16 + hi * 8];
            short8 bo = *(const short8*)(bpr + (ks << 9));
            acc = __builtin_amdgcn_mfma_f32_32x32x16_bf16(a, bo, acc, 0, 0, 0);
        }
    }

    // epilogue: C/D layout col=lane&31, row=(reg&3)+8*(reg>>2)+4*(lane>>5)
    float bs = bias[c0 + ln];
#pragma unroll
    for (int reg = 0; reg < 16; ++reg) {
        int row = (reg & 3) + 8 * (reg >> 2) + 4 * hi;
        int n = n0 + row;
        if (n < N_NODES)
            out[(size_t)n * OUT_DIM + c0 + ln] = fmaxf(acc[reg] + bs, 0.f);
    }
}

// --------------------------------------------------------------- launch ----
extern "C" void kernel_launch(void* const* d_in, const int* in_sizes, int n_in,
                              void* d_out, int out_size, void* d_ws, size_t ws_size,
                              hipStream_t stream) {
    const float* h      = (const float*)d_in[0];
    const float* basis  = (const float*)d_in[1];
    const float* w_comp = (const float*)d_in[2];
    const float* bias   = (const float*)d_in[3];
    const int*   src    = (const int*)d_in[4];
    const int*   dst    = (const int*)d_in[5];
    const int*   etype  = (const int*)d_in[6];
    float*       out    = (float*)d_out;

    char* ws = (char*)d_ws;
    size_t off = 0;
    unsigned short* U   = (unsigned short*)(ws + off); off += (size_t)N_NODES * KDIM * 2;          // 5.12 MB
    unsigned int*   S   = (unsigned int*)(ws + off);   off += (size_t)NUM_RELS * M_PAD * KDIM * 2; // 41.0 MB
    unsigned short* Bp  = (unsigned short*)(ws + off); off += (size_t)8 * 8 * 8 * 64 * 8 * 2;      // 0.52 MB
    int* cnt    = (int*)(ws + off); off += (size_t)M_PAD * 4;                                      // 80 KB
    int* bucket = (int*)(ws + off); off += ((size_t)M_PAD * CAP + 32) * 4;                         // 7.7 MB (+slack)

    hipMemsetAsync(cnt, 0, (size_t)N_NODES * 4, stream);

    prep_kernel<<<FOLD_BLOCKS + FILL_BLOCKS + BP_BLOCKS, 256, 0, stream>>>(
        h, w_comp, U, src, dst, etype, cnt, bucket, basis, Bp);

    aggregate_kernel<<<M_PAD / 4, 256, 0, stream>>>(U, cnt, bucket, S);

    gemm_kernel<<<M_PAD / 32, 512, 0, stream>>>((const unsigned short*)S, Bp, bias, out);
}